// Round 15
// baseline (1497.213 us; speedup 1.0000x reference)
//
#include <hip/hip_runtime.h>
#include <hip/hip_fp16.h>

#define NN 200000
#define EE 3200000
#define HID 32

// src-degree histogram v3: byte counters, 16KB tiles, packed partials
#define HB3 16384            // bins per group (16 KB LDS as bytes)
#define HG3 13               // 13*16384 = 212992 >= NN
#define HS3 80               // slices: grid = 13*80 = 1040
#define ESL3 (EE / HS3)      // 40000 edges per slice

// block-major two-stage dst sort, keyed by (dst>>10, src_range)
#define CH 8000    // edges per stage-A block (32 KB private region)
#define NA 400     // EE / CH
#define NBKT 196   // dst buckets of 1024
#define NKEY (NBKT * 4)      // 784

// src ranges: 4 x 50000 nodes -> 3.2 MB z-slice fits a 4 MB XCD L2
#define RSZ 50000

// phased prop v5: edge-balanced, 2048 co-resident blocks, 4 lanes x 16B/node
#define PPB2 2048

// cheb combine v6: fp16-staged rows, 2 outputs/thread, 16-node batches
#define CBLK3 1250
#define CBATCH3 10  // 1250*10*16 = 200000 = NN
#define NBAT 16

#define ALIGN64(p) ((char*)(((uintptr_t)(p) + 63) & ~(uintptr_t)63))

__device__ inline int srcrg(int s) {
    return (s >= RSZ) + (s >= 2 * RSZ) + (s >= 3 * RSZ);
}

// ---------------- fp16 helpers ----------------------------------------------

__device__ inline float4 ld_h4(const __half* p) {
    uint2 u = *reinterpret_cast<const uint2*>(p);
    __half2 a = *reinterpret_cast<__half2*>(&u.x);
    __half2 b = *reinterpret_cast<__half2*>(&u.y);
    float2 fa = __half22float2(a), fb = __half22float2(b);
    return make_float4(fa.x, fa.y, fb.x, fb.y);
}

__device__ inline void st_h4(__half* p, float4 v) {
    __half2 a = __floats2half2_rn(v.x, v.y);
    __half2 b = __floats2half2_rn(v.z, v.w);
    uint2 u;
    u.x = *reinterpret_cast<unsigned*>(&a);
    u.y = *reinterpret_cast<unsigned*>(&b);
    *reinterpret_cast<uint2*>(p) = u;
}

// accumulate 8 halfs (one uint4) into two float4s
__device__ inline void add8(float4& lo, float4& hi, uint4 u) {
    __half2 h0 = *reinterpret_cast<__half2*>(&u.x);
    __half2 h1 = *reinterpret_cast<__half2*>(&u.y);
    __half2 h2 = *reinterpret_cast<__half2*>(&u.z);
    __half2 h3 = *reinterpret_cast<__half2*>(&u.w);
    float2 f0 = __half22float2(h0), f1 = __half22float2(h1);
    float2 f2 = __half22float2(h2), f3 = __half22float2(h3);
    lo.x += f0.x; lo.y += f0.y; lo.z += f1.x; lo.w += f1.y;
    hi.x += f2.x; hi.y += f2.y; hi.z += f3.x; hi.w += f3.y;
}

// scale two float4s and store as 8 halfs (16B)
__device__ inline void st_h8s(__half* p, float4 lo, float4 hi, float sc) {
    __half2 h0 = __floats2half2_rn(sc * lo.x, sc * lo.y);
    __half2 h1 = __floats2half2_rn(sc * lo.z, sc * lo.w);
    __half2 h2 = __floats2half2_rn(sc * hi.x, sc * hi.y);
    __half2 h3 = __floats2half2_rn(sc * hi.z, sc * hi.w);
    uint4 u;
    u.x = *reinterpret_cast<unsigned*>(&h0);
    u.y = *reinterpret_cast<unsigned*>(&h1);
    u.z = *reinterpret_cast<unsigned*>(&h2);
    u.w = *reinterpret_cast<unsigned*>(&h3);
    *reinterpret_cast<uint4*>(p) = u;
}

// convert uint4 (8 halfs) -> 8 floats
__device__ inline void cvt8(uint4 u, float* f) {
    __half2 h0 = *reinterpret_cast<__half2*>(&u.x);
    __half2 h1 = *reinterpret_cast<__half2*>(&u.y);
    __half2 h2 = *reinterpret_cast<__half2*>(&u.z);
    __half2 h3 = *reinterpret_cast<__half2*>(&u.w);
    float2 f0 = __half22float2(h0), f1 = __half22float2(h1);
    float2 f2 = __half22float2(h2), f3 = __half22float2(h3);
    f[0] = f0.x; f[1] = f0.y; f[2] = f1.x; f[3] = f1.y;
    f[4] = f2.x; f[5] = f2.y; f[6] = f3.x; f[7] = f3.y;
}

// ---------------- src-degree histogram (byte-packed) ------------------------

__global__ __launch_bounds__(256) void k_hist(const int* __restrict__ vals,
                                              unsigned* __restrict__ partial) {
    __shared__ unsigned h[HB3 / 4];
    int blk = blockIdx.x;
    int g = blk % HG3, s = blk / HG3;
    int base = g * HB3;
    for (int i = threadIdx.x; i < HB3 / 4; i += 256) h[i] = 0;
    __syncthreads();
    const int4* p4 = reinterpret_cast<const int4*>(vals + (size_t)s * ESL3);
    for (int i = threadIdx.x; i < ESL3 / 4; i += 256) {
        int4 v = p4[i];
        int a0 = v.x - base, a1 = v.y - base, a2 = v.z - base, a3 = v.w - base;
        if ((unsigned)a0 < HB3) atomicAdd(&h[a0 >> 2], 1u << ((a0 & 3) * 8));
        if ((unsigned)a1 < HB3) atomicAdd(&h[a1 >> 2], 1u << ((a1 & 3) * 8));
        if ((unsigned)a2 < HB3) atomicAdd(&h[a2 >> 2], 1u << ((a2 & 3) * 8));
        if ((unsigned)a3 < HB3) atomicAdd(&h[a3 >> 2], 1u << ((a3 & 3) * 8));
    }
    __syncthreads();
    unsigned* out = partial + ((size_t)g * HS3 + s) * (HB3 / 4);
    for (int i = threadIdx.x; i < HB3 / 4; i += 256) out[i] = h[i];
}

__global__ void k_hredscale(const unsigned* __restrict__ partial,
                            float* __restrict__ dinv, float* __restrict__ d2,
                            float* __restrict__ sarr) {
    int q = blockIdx.x * 256 + threadIdx.x;
    if (q >= NN / 4) return;
    int nb = q * 4;
    int g = nb >> 14;
    int col = (nb & (HB3 - 1)) >> 2;
    const unsigned* p = partial + (size_t)g * HS3 * (HB3 / 4) + col;
    unsigned ssum = 0;
#pragma unroll
    for (int s = 0; s < HS3; s++) ssum += p[(size_t)s * (HB3 / 4)];
#pragma unroll
    for (int k = 0; k < 4; k++) {
        int n = nb + k;
        int d = (ssum >> (k * 8)) & 255;
        float di = d > 0 ? rsqrtf((float)d) : 0.f;
        dinv[n] = di;
        d2[n] = -di * di;
        sarr[n] = d > 0 ? 1.f / di : 0.f;
    }
}

// ---------------- stage A: block-major coarse sort by (bucket, src-range) ---

__global__ __launch_bounds__(256) void k_stageA(const int* __restrict__ ei,
                                                int* __restrict__ fs,
                                                int* __restrict__ ebkt) {
    __shared__ int sdst[CH];
    __shared__ int hist[NKEY], excl[NKEY + 1], rank[NKEY], s1[256];
    int blk = blockIdx.x, tid = threadIdx.x;
    for (int i = tid; i < NKEY; i += 256) { hist[i] = 0; rank[i] = 0; }
    __syncthreads();
    const int* dptr = ei + EE + (size_t)blk * CH;
    const int* sptr = ei + (size_t)blk * CH;
    for (int i = tid; i < CH; i += 256) {
        int d = dptr[i], s = sptr[i];
        sdst[i] = d;
        atomicAdd(&hist[(d >> 10) * 4 + srcrg(s)], 1);
    }
    __syncthreads();
    int b4 = tid * 4;
    int v0 = (b4 < NKEY) ? hist[b4] : 0;
    int v1 = (b4 + 1 < NKEY) ? hist[b4 + 1] : 0;
    int v2 = (b4 + 2 < NKEY) ? hist[b4 + 2] : 0;
    int v3 = (b4 + 3 < NKEY) ? hist[b4 + 3] : 0;
    int ts = v0 + v1 + v2 + v3;
    s1[tid] = ts;
    __syncthreads();
    for (int off = 1; off < 256; off <<= 1) {
        int t2 = (tid >= off) ? s1[tid - off] : 0;
        __syncthreads();
        s1[tid] += t2;
        __syncthreads();
    }
    int te = s1[tid] - ts;
    if (b4 < NKEY) excl[b4] = te;
    if (b4 + 1 < NKEY) excl[b4 + 1] = te + v0;
    if (b4 + 2 < NKEY) excl[b4 + 2] = te + v0 + v1;
    if (b4 + 3 < NKEY) excl[b4 + 3] = te + v0 + v1 + v2;
    if (tid == 0) excl[NKEY] = CH;
    __syncthreads();
    for (int k = tid; k <= NKEY; k += 256) fs[(size_t)k * NA + blk] = excl[k];
    int base = blk * CH;
    for (int i = tid; i < CH; i += 256) {
        int d = sdst[i], s = sptr[i];
        int key = (d >> 10) * 4 + srcrg(s);
        int r = atomicAdd(&rank[key], 1);
        ebkt[base + excl[key] + r] = (s << 10) | (d & 1023);
    }
}

// ---------------- key totals + exclusive scan (range-major output) ----------

__global__ void k_btot(const int* __restrict__ fs, int* __restrict__ btot) {
    __shared__ int s[256];
    int k = blockIdx.x, tid = threadIdx.x;
    int sum = 0;
    for (int blk = tid; blk < NA; blk += 256)
        sum += fs[(size_t)(k + 1) * NA + blk] - fs[(size_t)k * NA + blk];
    s[tid] = sum;
    __syncthreads();
    for (int off = 128; off > 0; off >>= 1) {
        if (tid < off) s[tid] += s[tid + off];
        __syncthreads();
    }
    if (tid == 0) btot[k] = s[0];
}

__global__ void k_bscan(const int* __restrict__ btot, int* __restrict__ bstart2) {
    __shared__ int s[256];
    __shared__ int carry;
    int tid = threadIdx.x;
    if (tid == 0) carry = 0;
    __syncthreads();
    for (int base = 0; base < NKEY; base += 256) {
        int m = base + tid;
        int v = 0;
        if (m < NKEY) v = btot[(m % NBKT) * 4 + (m / NBKT)];
        s[tid] = v;
        __syncthreads();
        for (int off = 1; off < 256; off <<= 1) {
            int t = (tid >= off) ? s[tid - off] : 0;
            __syncthreads();
            s[tid] += t;
            __syncthreads();
        }
        int excl = s[tid] - v + carry;
        if (m < NKEY) bstart2[m] = excl;
        __syncthreads();
        if (tid == 0) carry += s[255];
        __syncthreads();
    }
    if (tid == 0) bstart2[NKEY] = EE;
}

// ---------------- stage B: bucket -> range-segmented exact CSR + rowptr2 ----

__global__ __launch_bounds__(1024) void k_stageB(const int* __restrict__ fs,
                                                 const int* __restrict__ bstart2,
                                                 const int* __restrict__ ebkt,
                                                 int* __restrict__ rowptr2,
                                                 int* __restrict__ csr) {
    __shared__ int ls0[NA], llen[NA];
    __shared__ int deg[4096], excl[4096], rank[4096], s1[1024];
    __shared__ int sb[4], seg0[4];
    int b = blockIdx.x, tid = threadIdx.x;
    if (tid < NA) {
        int o0 = fs[(size_t)(4 * b) * NA + tid];
        int o1 = fs[(size_t)(4 * b + 4) * NA + tid];
        ls0[tid] = tid * CH + o0;
        llen[tid] = o1 - o0;
    }
    deg[tid] = 0; deg[tid + 1024] = 0; deg[tid + 2048] = 0; deg[tid + 3072] = 0;
    rank[tid] = 0; rank[tid + 1024] = 0; rank[tid + 2048] = 0; rank[tid + 3072] = 0;
    if (tid < 4) sb[tid] = bstart2[tid * NBKT + b];
    __syncthreads();
    int wave = tid >> 6, lane = tid & 63;   // 16 waves
    for (int f = wave; f < NA; f += 16) {
        int base = ls0[f], len = llen[f];
        for (int k = lane; k < len; k += 64) {
            int e = ebkt[base + k];
            int s = e >> 10, l = e & 1023;
            atomicAdd(&deg[srcrg(s) * 1024 + l], 1);
        }
    }
    __syncthreads();
    int v0 = deg[4 * tid], v1 = deg[4 * tid + 1];
    int v2 = deg[4 * tid + 2], v3 = deg[4 * tid + 3];
    int ts = v0 + v1 + v2 + v3;
    s1[tid] = ts;
    __syncthreads();
    for (int off = 1; off < 1024; off <<= 1) {
        int t = (tid >= off) ? s1[tid - off] : 0;
        __syncthreads();
        s1[tid] += t;
        __syncthreads();
    }
    int te = s1[tid] - ts;
    excl[4 * tid] = te;
    excl[4 * tid + 1] = te + v0;
    excl[4 * tid + 2] = te + v0 + v1;
    excl[4 * tid + 3] = te + v0 + v1 + v2;
    __syncthreads();
    if (tid < 4) seg0[tid] = excl[tid * 1024];
    __syncthreads();
#pragma unroll
    for (int k = 0; k < 4; k++) {
        int m = 4 * tid + k;
        int rg = m >> 10, l = m & 1023;
        int node = (b << 10) + l;
        if (node <= NN)
            rowptr2[(size_t)rg * (NN + 1) + node] = sb[rg] + excl[m] - seg0[rg];
    }
    for (int f = wave; f < NA; f += 16) {
        int base = ls0[f], len = llen[f];
        for (int k = lane; k < len; k += 64) {
            int e = ebkt[base + k];
            int s = e >> 10, l = e & 1023;
            int rg = srcrg(s);
            int key = rg * 1024 + l;
            int r = atomicAdd(&rank[key], 1);
            csr[sb[rg] + (excl[key] - seg0[rg]) + r] = s;
        }
    }
}

// ---------------- edge-balanced block partition -----------------------------

__global__ void k_bal(const int* __restrict__ rowptr2, int* __restrict__ nb) {
    int b = blockIdx.x * 256 + threadIdx.x;
    if (b > PPB2) return;
    if (b == 0) { nb[0] = 0; return; }
    if (b == PPB2) { nb[PPB2] = NN; return; }
    long cum0 = 0;
#pragma unroll
    for (int r = 0; r < 4; r++) cum0 += rowptr2[(size_t)r * (NN + 1)];
    long target = (long)b * EE / PPB2 + cum0;
    int lo = 0, hi = NN;
    while (lo < hi) {
        int mid = (lo + hi) >> 1;
        long cm = 0;
#pragma unroll
        for (int r = 0; r < 4; r++) cm += rowptr2[(size_t)r * (NN + 1) + mid];
        if (cm < target) lo = mid + 1; else hi = mid;
    }
    nb[b] = lo;
}

// ---------------- input MLP: writes T-linear + z-linear ---------------------

__global__ void k_mlp0(const float* __restrict__ x, const float* __restrict__ W0,
                       const float* __restrict__ b0, __half* __restrict__ outT,
                       __half* __restrict__ outZ, const float* __restrict__ dinv) {
    int t = blockIdx.x * 256 + threadIdx.x;
    int n = t >> 5, o = t & 31;
    if (n < NN) {
        float acc = b0[o];
#pragma unroll
        for (int i = 0; i < 3; i++) acc += x[n * 3 + i] * W0[i * 32 + o];
        float h = fmaxf(acc, 0.f);
        outT[t] = __float2half(h);
        outZ[t] = __float2half(dinv[n] * h);
    }
}

// ---------------- phased z-space propagation v5 -----------------------------

__device__ inline void accum_range4(const int* __restrict__ rp,
                                    const int* __restrict__ csr,
                                    const __half* __restrict__ zc,
                                    int n, float4& lo, float4& hi) {
    int j = rp[n], end = rp[n + 1];
    for (; j + 4 <= end; j += 4) {
        int4 e = *reinterpret_cast<const int4*>(csr + j);
        uint4 u0 = *reinterpret_cast<const uint4*>(zc + (size_t)e.x * 32);
        uint4 u1 = *reinterpret_cast<const uint4*>(zc + (size_t)e.y * 32);
        uint4 u2 = *reinterpret_cast<const uint4*>(zc + (size_t)e.z * 32);
        uint4 u3 = *reinterpret_cast<const uint4*>(zc + (size_t)e.w * 32);
        add8(lo, hi, u0); add8(lo, hi, u1); add8(lo, hi, u2); add8(lo, hi, u3);
    }
    for (; j < end; j++) {
        uint4 u = *reinterpret_cast<const uint4*>(zc + (size_t)csr[j] * 32);
        add8(lo, hi, u);
    }
}

__global__ __launch_bounds__(256, 8) void k_prop2(const int* __restrict__ rowptr2,
                                                  const int* __restrict__ csr,
                                                  const int* __restrict__ nb,
                                                  const __half* __restrict__ zin,
                                                  __half* __restrict__ zout,
                                                  const float* __restrict__ d2) {
    int tid = threadIdx.x;
    int g = tid >> 2, c = tid & 3;          // 64 node-groups, 4 lanes each
    int start = nb[blockIdx.x], end = nb[blockIdx.x + 1];
    const __half* zc = zin + c * 8;
    int n0 = start + g;
    float4 zz = make_float4(0.f, 0.f, 0.f, 0.f);
    float4 l0 = zz, h0 = zz, l1 = zz, h1 = zz, l2 = zz, h2 = zz;
    for (int r = 0; r < 4; r++) {
        const int* rp = rowptr2 + (size_t)r * (NN + 1);
        if (n0       < end) accum_range4(rp, csr, zc, n0,       l0, h0);
        if (n0 + 64  < end) accum_range4(rp, csr, zc, n0 + 64,  l1, h1);
        if (n0 + 128 < end) accum_range4(rp, csr, zc, n0 + 128, l2, h2);
        // no barrier: edge-balance keeps blocks phase-aligned
    }
    if (n0 < end)
        st_h8s(zout + (size_t)n0 * 32 + c * 8, l0, h0, d2[n0]);
    if (n0 + 64 < end)
        st_h8s(zout + (size_t)(n0 + 64) * 32 + c * 8, l1, h1, d2[n0 + 64]);
    if (n0 + 128 < end)
        st_h8s(zout + (size_t)(n0 + 128) * 32 + c * 8, l2, h2, d2[n0 + 128]);
}

// ---------------- fused Cheb combine v6 -------------------------------------
// fp16-staged rows (lossless copy; convert at consume) + 2 adjacent outputs
// per thread (16 threads/node, 16-node batches): LDS reads per output drop
// 4x vs v5 (12 ds_read_b128 per thread-batch serving 2 outputs). Same fp32
// math. Double-buffered, prefetch, one barrier per batch.

__global__ __launch_bounds__(256, 2) void k_cheb(const __half* __restrict__ T0,
                                                 const __half* __restrict__ Z1,
                                                 const __half* __restrict__ Z2,
                                                 const __half* __restrict__ res,
                                                 __half* __restrict__ outT,
                                                 __half* __restrict__ outZ,
                                                 const float* __restrict__ W,
                                                 const float* __restrict__ b,
                                                 const float* __restrict__ sarr,
                                                 const float* __restrict__ dinv,
                                                 int do_relu, int has_res, int write_z) {
    __shared__ __align__(16) __half A[2][3][NBAT * 32];  // raw fp16 rows, 6KB
    __shared__ __align__(16) float R[2][NBAT][32];       // res fp32, 4KB
    int t = threadIdx.x;
    int oo = t & 15, ng = t >> 4;       // node ng (0..15), outputs 2oo, 2oo+1
    int a = t >> 6, j = t & 63;         // staging: wave a stages array a

    // two adjacent weight columns per thread
    float w0p[2][32], w1c[2][32], w2p[2][32];
#pragma unroll
    for (int hh = 0; hh < 2; hh++) {
        int o = 2 * oo + hh;
#pragma unroll
        for (int i = 0; i < 32; i++) {
            float wa = W[i * 32 + o];
            float wb = W[1024 + i * 32 + o];
            float wc = W[2048 + i * 32 + o];
            w0p[hh][i] = wa - wc;
            w1c[hh][i] = wb;
            w2p[hh][i] = 2.f * wc;
        }
    }
    float bias0 = b[2 * oo], bias1 = b[2 * oo + 1];

    bool active = (a < 3) || has_res;
    const __half* srcp = (a == 0) ? T0 : (a == 1) ? Z1 : (a == 2) ? Z2 : res;
    int bt0 = blockIdx.x * CBATCH3;

    // prologue: stage batch 0 into buffer 0
    if (active) {
        uint4 u = *(reinterpret_cast<const uint4*>(srcp + (size_t)bt0 * NBAT * 32) + j);
        if (a < 3) {
            *reinterpret_cast<uint4*>(&A[0][a][j * 8]) = u;
        } else {
            float f[8];
            cvt8(u, f);
            float* dst = &R[0][j >> 2][(j & 3) * 8];
#pragma unroll
            for (int k = 0; k < 8; k++) dst[k] = f[k];
        }
    }
    __syncthreads();

    int cur = 0;
    for (int bt = bt0; bt < bt0 + CBATCH3; bt++) {
        uint4 un;
        bool pf = active && (bt + 1 < bt0 + CBATCH3);
        if (pf)
            un = *(reinterpret_cast<const uint4*>(srcp + (size_t)(bt + 1) * NBAT * 32) + j);

        size_t base = (size_t)bt * NBAT * 32;
        float accA0 = bias0, accA1 = bias1;
        if (has_res) {
            float2 rr = *reinterpret_cast<float2*>(&R[cur][ng][2 * oo]);
            accA0 += rr.x; accA1 += rr.y;
        }
        float accB0 = 0.f, accB1 = 0.f;
        const __half* rowT = &A[cur][0][ng * 32];
        const __half* row1 = &A[cur][1][ng * 32];
        const __half* row2 = &A[cur][2][ng * 32];
#pragma unroll
        for (int q = 0; q < 4; q++) {
            uint4 uT = *reinterpret_cast<const uint4*>(rowT + q * 8);
            uint4 u1 = *reinterpret_cast<const uint4*>(row1 + q * 8);
            uint4 u2 = *reinterpret_cast<const uint4*>(row2 + q * 8);
            float fT[8], f1[8], f2[8];
            cvt8(uT, fT); cvt8(u1, f1); cvt8(u2, f2);
#pragma unroll
            for (int k = 0; k < 8; k++) {
                int i = q * 8 + k;
                accA0 += fT[k] * w0p[0][i];
                accA1 += fT[k] * w0p[1][i];
                accB0 += f1[k] * w1c[0][i] + f2[k] * w2p[0][i];
                accB1 += f1[k] * w1c[1][i] + f2[k] * w2p[1][i];
            }
        }
        int node = bt * NBAT + ng;
        float s = sarr[node];
        float v0 = accA0 + s * accB0;
        float v1 = accA1 + s * accB1;
        if (do_relu) { v0 = fmaxf(v0, 0.f); v1 = fmaxf(v1, 0.f); }
        __half2 hv = __floats2half2_rn(v0, v1);
        *reinterpret_cast<unsigned*>(outT + base + ng * 32 + 2 * oo) =
            *reinterpret_cast<unsigned*>(&hv);
        if (write_z) {
            float dv = dinv[node];
            __half2 hz = __floats2half2_rn(dv * v0, dv * v1);
            *reinterpret_cast<unsigned*>(outZ + base + ng * 32 + 2 * oo) =
                *reinterpret_cast<unsigned*>(&hz);
        }

        if (pf) {
            if (a < 3) {
                *reinterpret_cast<uint4*>(&A[cur ^ 1][a][j * 8]) = un;
            } else {
                float f[8];
                cvt8(un, f);
                float* dst = &R[cur ^ 1][j >> 2][(j & 3) * 8];
#pragma unroll
                for (int k = 0; k < 8; k++) dst[k] = f[k];
            }
        }
        __syncthreads();   // cur fully read + cur^1 staged
        cur ^= 1;
    }
}

// ---------------- final head ------------------------------------------------

__global__ void k_final(const __half* __restrict__ X, const float* __restrict__ W1,
                        const float* __restrict__ b1, float* __restrict__ out) {
    int n = blockIdx.x * 256 + threadIdx.x;
    if (n < NN) {
        float acc = b1[0];
        const __half* xp = X + (size_t)n * 32;
#pragma unroll
        for (int c = 0; c < 8; c++) {
            float4 v = ld_h4(xp + c * 4);
            acc += v.x * W1[c * 4 + 0] + v.y * W1[c * 4 + 1] +
                   v.z * W1[c * 4 + 2] + v.w * W1[c * 4 + 3];
        }
        out[n] = acc;
    }
}

extern "C" void kernel_launch(void* const* d_in, const int* in_sizes, int n_in,
                              void* d_out, int out_size, void* d_ws, size_t ws_size,
                              hipStream_t stream) {
    const float* x    = (const float*)d_in[0];
    const int*   ei   = (const int*)d_in[1];
    const float* W0   = (const float*)d_in[2];
    const float* b0   = (const float*)d_in[3];
    const float* c11W = (const float*)d_in[4];
    const float* c11b = (const float*)d_in[5];
    const float* c12W = (const float*)d_in[6];
    const float* c12b = (const float*)d_in[7];
    const float* c21W = (const float*)d_in[8];
    const float* c21b = (const float*)d_in[9];
    const float* c22W = (const float*)d_in[10];
    const float* c22b = (const float*)d_in[11];
    const float* W1   = (const float*)d_in[12];
    const float* b1   = (const float*)d_in[13];
    float* out = (float*)d_out;

    char* ws = (char*)d_ws;
    float* dinv = (float*)ws;  ws = ALIGN64(ws + (size_t)NN * 4);
    float* d2 = (float*)ws;    ws = ALIGN64(ws + (size_t)NN * 4);
    float* sarr = (float*)ws;  ws = ALIGN64(ws + (size_t)NN * 4);
    int* rowptr2 = (int*)ws;   ws = ALIGN64(ws + (size_t)4 * (NN + 1) * 4);
    int* nb = (int*)ws;        ws = ALIGN64(ws + (size_t)(PPB2 + 1) * 4);
    unsigned* partial = (unsigned*)ws;
    ws = ALIGN64(ws + (size_t)HG3 * HS3 * (HB3 / 4) * 4);          // 17.0 MB
    int* fs = (int*)ws;        ws = ALIGN64(ws + (size_t)(NKEY + 1) * NA * 4);
    int* btot = (int*)ws;      ws = ALIGN64(ws + (size_t)NKEY * 4);
    int* bstart2 = (int*)ws;   ws = ALIGN64(ws + (size_t)(NKEY + 1) * 4);
    int* ebkt = (int*)ws;      ws = ALIGN64(ws + (size_t)EE * 4);  // 12.8 MB
    int* csr = (int*)ws;       ws = ALIGN64(ws + (size_t)EE * 4);  // 12.8 MB
    __half* F0 = (__half*)ws;  ws = ALIGN64(ws + (size_t)NN * HID * 2);
    __half* F1 = (__half*)ws;  ws = ALIGN64(ws + (size_t)NN * HID * 2);
    __half* Zin = (__half*)ws; ws = ALIGN64(ws + (size_t)NN * HID * 2);
    __half* Zb1 = (__half*)ws; ws = ALIGN64(ws + (size_t)NN * HID * 2);
    __half* Zb2 = (__half*)ws; ws = ALIGN64(ws + (size_t)NN * HID * 2);

    // src degrees -> dinv, d2, s
    k_hist<<<HG3 * HS3, 256, 0, stream>>>(ei, partial);
    k_hredscale<<<NN / 4 / 256 + 1, 256, 0, stream>>>(partial, dinv, d2, sarr);

    // two-stage sort -> range-segmented exact CSR + rowptr2
    k_stageA<<<NA, 256, 0, stream>>>(ei, fs, ebkt);
    k_btot<<<NKEY, 256, 0, stream>>>(fs, btot);
    k_bscan<<<1, 256, 0, stream>>>(btot, bstart2);
    k_stageB<<<NBKT, 1024, 0, stream>>>(fs, bstart2, ebkt, rowptr2, csr);

    // edge-balanced block partition for phased prop
    k_bal<<<(PPB2 + 256) / 256, 256, 0, stream>>>(rowptr2, nb);

    k_mlp0<<<NN * HID / 256, 256, 0, stream>>>(x, W0, b0, F0, Zin, dinv);

    auto conv = [&](const __half* T0, const __half* res, __half* outT,
                    const float* W, const float* b, int relu, int has_res, int wz) {
        k_prop2<<<PPB2, 256, 0, stream>>>(rowptr2, csr, nb, Zin, Zb1, d2);
        k_prop2<<<PPB2, 256, 0, stream>>>(rowptr2, csr, nb, Zb1, Zb2, d2);
        k_cheb<<<CBLK3, 256, 0, stream>>>(T0, Zb1, Zb2, res, outT, Zin,
                                          W, b, sarr, dinv, relu, has_res, wz);
    };

    conv(F0, nullptr, F1, c11W, c11b, 1, 0, 1);   // block1 conv1
    conv(F1, F0,      F0, c12W, c12b, 1, 1, 1);   // block1 conv2 (+res)
    conv(F0, nullptr, F1, c21W, c21b, 1, 0, 1);   // block2 conv1
    conv(F1, F0,      F0, c22W, c22b, 1, 1, 0);   // block2 conv2 (+res, no z)

    k_final<<<(NN + 255) / 256, 256, 0, stream>>>(F0, W1, b1, out);
}

// Round 16
// 798.384 us; speedup vs baseline: 1.8753x; 1.8753x over previous
//
#include <hip/hip_runtime.h>
#include <hip/hip_fp16.h>

#define NN 200000
#define EE 3200000
#define HID 32

// src-degree histogram v3: byte counters, 16KB tiles, packed partials
#define HB3 16384            // bins per group (16 KB LDS as bytes)
#define HG3 13               // 13*16384 = 212992 >= NN
#define HS3 80               // slices: grid = 13*80 = 1040
#define ESL3 (EE / HS3)      // 40000 edges per slice

// block-major two-stage dst sort, keyed by (dst>>10, src_range)
#define CH 8000    // edges per stage-A block (32 KB private region)
#define NA 400     // EE / CH
#define NBKT 196   // dst buckets of 1024
#define NKEY (NBKT * 4)      // 784

// src ranges: 4 x 50000 nodes -> 3.2 MB z-slice fits a 4 MB XCD L2
#define RSZ 50000

// phased prop v5: edge-balanced, 2048 co-resident blocks, 4 lanes x 16B/node
#define PPB2 2048

// cheb combine v7: v5 structure (1 output/thread) + fp16-staged rows
#define CBLK2 3125
#define CBATCH2 8  // 3125*8*8 = 200000 = NN

#define ALIGN64(p) ((char*)(((uintptr_t)(p) + 63) & ~(uintptr_t)63))

__device__ inline int srcrg(int s) {
    return (s >= RSZ) + (s >= 2 * RSZ) + (s >= 3 * RSZ);
}

// ---------------- fp16 helpers ----------------------------------------------

__device__ inline float4 ld_h4(const __half* p) {
    uint2 u = *reinterpret_cast<const uint2*>(p);
    __half2 a = *reinterpret_cast<__half2*>(&u.x);
    __half2 b = *reinterpret_cast<__half2*>(&u.y);
    float2 fa = __half22float2(a), fb = __half22float2(b);
    return make_float4(fa.x, fa.y, fb.x, fb.y);
}

__device__ inline void st_h4(__half* p, float4 v) {
    __half2 a = __floats2half2_rn(v.x, v.y);
    __half2 b = __floats2half2_rn(v.z, v.w);
    uint2 u;
    u.x = *reinterpret_cast<unsigned*>(&a);
    u.y = *reinterpret_cast<unsigned*>(&b);
    *reinterpret_cast<uint2*>(p) = u;
}

// accumulate 8 halfs (one uint4) into two float4s
__device__ inline void add8(float4& lo, float4& hi, uint4 u) {
    __half2 h0 = *reinterpret_cast<__half2*>(&u.x);
    __half2 h1 = *reinterpret_cast<__half2*>(&u.y);
    __half2 h2 = *reinterpret_cast<__half2*>(&u.z);
    __half2 h3 = *reinterpret_cast<__half2*>(&u.w);
    float2 f0 = __half22float2(h0), f1 = __half22float2(h1);
    float2 f2 = __half22float2(h2), f3 = __half22float2(h3);
    lo.x += f0.x; lo.y += f0.y; lo.z += f1.x; lo.w += f1.y;
    hi.x += f2.x; hi.y += f2.y; hi.z += f3.x; hi.w += f3.y;
}

// scale two float4s and store as 8 halfs (16B)
__device__ inline void st_h8s(__half* p, float4 lo, float4 hi, float sc) {
    __half2 h0 = __floats2half2_rn(sc * lo.x, sc * lo.y);
    __half2 h1 = __floats2half2_rn(sc * lo.z, sc * lo.w);
    __half2 h2 = __floats2half2_rn(sc * hi.x, sc * hi.y);
    __half2 h3 = __floats2half2_rn(sc * hi.z, sc * hi.w);
    uint4 u;
    u.x = *reinterpret_cast<unsigned*>(&h0);
    u.y = *reinterpret_cast<unsigned*>(&h1);
    u.z = *reinterpret_cast<unsigned*>(&h2);
    u.w = *reinterpret_cast<unsigned*>(&h3);
    *reinterpret_cast<uint4*>(p) = u;
}

// convert uint4 (8 halfs) -> 8 floats
__device__ inline void cvt8(uint4 u, float* f) {
    __half2 h0 = *reinterpret_cast<__half2*>(&u.x);
    __half2 h1 = *reinterpret_cast<__half2*>(&u.y);
    __half2 h2 = *reinterpret_cast<__half2*>(&u.z);
    __half2 h3 = *reinterpret_cast<__half2*>(&u.w);
    float2 f0 = __half22float2(h0), f1 = __half22float2(h1);
    float2 f2 = __half22float2(h2), f3 = __half22float2(h3);
    f[0] = f0.x; f[1] = f0.y; f[2] = f1.x; f[3] = f1.y;
    f[4] = f2.x; f[5] = f2.y; f[6] = f3.x; f[7] = f3.y;
}

// ---------------- src-degree histogram (byte-packed) ------------------------

__global__ __launch_bounds__(256) void k_hist(const int* __restrict__ vals,
                                              unsigned* __restrict__ partial) {
    __shared__ unsigned h[HB3 / 4];
    int blk = blockIdx.x;
    int g = blk % HG3, s = blk / HG3;
    int base = g * HB3;
    for (int i = threadIdx.x; i < HB3 / 4; i += 256) h[i] = 0;
    __syncthreads();
    const int4* p4 = reinterpret_cast<const int4*>(vals + (size_t)s * ESL3);
    for (int i = threadIdx.x; i < ESL3 / 4; i += 256) {
        int4 v = p4[i];
        int a0 = v.x - base, a1 = v.y - base, a2 = v.z - base, a3 = v.w - base;
        if ((unsigned)a0 < HB3) atomicAdd(&h[a0 >> 2], 1u << ((a0 & 3) * 8));
        if ((unsigned)a1 < HB3) atomicAdd(&h[a1 >> 2], 1u << ((a1 & 3) * 8));
        if ((unsigned)a2 < HB3) atomicAdd(&h[a2 >> 2], 1u << ((a2 & 3) * 8));
        if ((unsigned)a3 < HB3) atomicAdd(&h[a3 >> 2], 1u << ((a3 & 3) * 8));
    }
    __syncthreads();
    unsigned* out = partial + ((size_t)g * HS3 + s) * (HB3 / 4);
    for (int i = threadIdx.x; i < HB3 / 4; i += 256) out[i] = h[i];
}

__global__ void k_hredscale(const unsigned* __restrict__ partial,
                            float* __restrict__ dinv, float* __restrict__ d2,
                            float* __restrict__ sarr) {
    int q = blockIdx.x * 256 + threadIdx.x;
    if (q >= NN / 4) return;
    int nb = q * 4;
    int g = nb >> 14;
    int col = (nb & (HB3 - 1)) >> 2;
    const unsigned* p = partial + (size_t)g * HS3 * (HB3 / 4) + col;
    unsigned ssum = 0;
#pragma unroll
    for (int s = 0; s < HS3; s++) ssum += p[(size_t)s * (HB3 / 4)];
#pragma unroll
    for (int k = 0; k < 4; k++) {
        int n = nb + k;
        int d = (ssum >> (k * 8)) & 255;
        float di = d > 0 ? rsqrtf((float)d) : 0.f;
        dinv[n] = di;
        d2[n] = -di * di;
        sarr[n] = d > 0 ? 1.f / di : 0.f;
    }
}

// ---------------- stage A: block-major coarse sort by (bucket, src-range) ---

__global__ __launch_bounds__(256) void k_stageA(const int* __restrict__ ei,
                                                int* __restrict__ fs,
                                                int* __restrict__ ebkt) {
    __shared__ int sdst[CH];
    __shared__ int hist[NKEY], excl[NKEY + 1], rank[NKEY], s1[256];
    int blk = blockIdx.x, tid = threadIdx.x;
    for (int i = tid; i < NKEY; i += 256) { hist[i] = 0; rank[i] = 0; }
    __syncthreads();
    const int* dptr = ei + EE + (size_t)blk * CH;
    const int* sptr = ei + (size_t)blk * CH;
    for (int i = tid; i < CH; i += 256) {
        int d = dptr[i], s = sptr[i];
        sdst[i] = d;
        atomicAdd(&hist[(d >> 10) * 4 + srcrg(s)], 1);
    }
    __syncthreads();
    int b4 = tid * 4;
    int v0 = (b4 < NKEY) ? hist[b4] : 0;
    int v1 = (b4 + 1 < NKEY) ? hist[b4 + 1] : 0;
    int v2 = (b4 + 2 < NKEY) ? hist[b4 + 2] : 0;
    int v3 = (b4 + 3 < NKEY) ? hist[b4 + 3] : 0;
    int ts = v0 + v1 + v2 + v3;
    s1[tid] = ts;
    __syncthreads();
    for (int off = 1; off < 256; off <<= 1) {
        int t2 = (tid >= off) ? s1[tid - off] : 0;
        __syncthreads();
        s1[tid] += t2;
        __syncthreads();
    }
    int te = s1[tid] - ts;
    if (b4 < NKEY) excl[b4] = te;
    if (b4 + 1 < NKEY) excl[b4 + 1] = te + v0;
    if (b4 + 2 < NKEY) excl[b4 + 2] = te + v0 + v1;
    if (b4 + 3 < NKEY) excl[b4 + 3] = te + v0 + v1 + v2;
    if (tid == 0) excl[NKEY] = CH;
    __syncthreads();
    for (int k = tid; k <= NKEY; k += 256) fs[(size_t)k * NA + blk] = excl[k];
    int base = blk * CH;
    for (int i = tid; i < CH; i += 256) {
        int d = sdst[i], s = sptr[i];
        int key = (d >> 10) * 4 + srcrg(s);
        int r = atomicAdd(&rank[key], 1);
        ebkt[base + excl[key] + r] = (s << 10) | (d & 1023);
    }
}

// ---------------- key totals + exclusive scan (range-major output) ----------

__global__ void k_btot(const int* __restrict__ fs, int* __restrict__ btot) {
    __shared__ int s[256];
    int k = blockIdx.x, tid = threadIdx.x;
    int sum = 0;
    for (int blk = tid; blk < NA; blk += 256)
        sum += fs[(size_t)(k + 1) * NA + blk] - fs[(size_t)k * NA + blk];
    s[tid] = sum;
    __syncthreads();
    for (int off = 128; off > 0; off >>= 1) {
        if (tid < off) s[tid] += s[tid + off];
        __syncthreads();
    }
    if (tid == 0) btot[k] = s[0];
}

__global__ void k_bscan(const int* __restrict__ btot, int* __restrict__ bstart2) {
    __shared__ int s[256];
    __shared__ int carry;
    int tid = threadIdx.x;
    if (tid == 0) carry = 0;
    __syncthreads();
    for (int base = 0; base < NKEY; base += 256) {
        int m = base + tid;
        int v = 0;
        if (m < NKEY) v = btot[(m % NBKT) * 4 + (m / NBKT)];
        s[tid] = v;
        __syncthreads();
        for (int off = 1; off < 256; off <<= 1) {
            int t = (tid >= off) ? s[tid - off] : 0;
            __syncthreads();
            s[tid] += t;
            __syncthreads();
        }
        int excl = s[tid] - v + carry;
        if (m < NKEY) bstart2[m] = excl;
        __syncthreads();
        if (tid == 0) carry += s[255];
        __syncthreads();
    }
    if (tid == 0) bstart2[NKEY] = EE;
}

// ---------------- stage B: bucket -> range-segmented exact CSR + rowptr2 ----

__global__ __launch_bounds__(1024) void k_stageB(const int* __restrict__ fs,
                                                 const int* __restrict__ bstart2,
                                                 const int* __restrict__ ebkt,
                                                 int* __restrict__ rowptr2,
                                                 int* __restrict__ csr) {
    __shared__ int ls0[NA], llen[NA];
    __shared__ int deg[4096], excl[4096], rank[4096], s1[1024];
    __shared__ int sb[4], seg0[4];
    int b = blockIdx.x, tid = threadIdx.x;
    if (tid < NA) {
        int o0 = fs[(size_t)(4 * b) * NA + tid];
        int o1 = fs[(size_t)(4 * b + 4) * NA + tid];
        ls0[tid] = tid * CH + o0;
        llen[tid] = o1 - o0;
    }
    deg[tid] = 0; deg[tid + 1024] = 0; deg[tid + 2048] = 0; deg[tid + 3072] = 0;
    rank[tid] = 0; rank[tid + 1024] = 0; rank[tid + 2048] = 0; rank[tid + 3072] = 0;
    if (tid < 4) sb[tid] = bstart2[tid * NBKT + b];
    __syncthreads();
    int wave = tid >> 6, lane = tid & 63;   // 16 waves
    for (int f = wave; f < NA; f += 16) {
        int base = ls0[f], len = llen[f];
        for (int k = lane; k < len; k += 64) {
            int e = ebkt[base + k];
            int s = e >> 10, l = e & 1023;
            atomicAdd(&deg[srcrg(s) * 1024 + l], 1);
        }
    }
    __syncthreads();
    int v0 = deg[4 * tid], v1 = deg[4 * tid + 1];
    int v2 = deg[4 * tid + 2], v3 = deg[4 * tid + 3];
    int ts = v0 + v1 + v2 + v3;
    s1[tid] = ts;
    __syncthreads();
    for (int off = 1; off < 1024; off <<= 1) {
        int t = (tid >= off) ? s1[tid - off] : 0;
        __syncthreads();
        s1[tid] += t;
        __syncthreads();
    }
    int te = s1[tid] - ts;
    excl[4 * tid] = te;
    excl[4 * tid + 1] = te + v0;
    excl[4 * tid + 2] = te + v0 + v1;
    excl[4 * tid + 3] = te + v0 + v1 + v2;
    __syncthreads();
    if (tid < 4) seg0[tid] = excl[tid * 1024];
    __syncthreads();
#pragma unroll
    for (int k = 0; k < 4; k++) {
        int m = 4 * tid + k;
        int rg = m >> 10, l = m & 1023;
        int node = (b << 10) + l;
        if (node <= NN)
            rowptr2[(size_t)rg * (NN + 1) + node] = sb[rg] + excl[m] - seg0[rg];
    }
    for (int f = wave; f < NA; f += 16) {
        int base = ls0[f], len = llen[f];
        for (int k = lane; k < len; k += 64) {
            int e = ebkt[base + k];
            int s = e >> 10, l = e & 1023;
            int rg = srcrg(s);
            int key = rg * 1024 + l;
            int r = atomicAdd(&rank[key], 1);
            csr[sb[rg] + (excl[key] - seg0[rg]) + r] = s;
        }
    }
}

// ---------------- edge-balanced block partition -----------------------------

__global__ void k_bal(const int* __restrict__ rowptr2, int* __restrict__ nb) {
    int b = blockIdx.x * 256 + threadIdx.x;
    if (b > PPB2) return;
    if (b == 0) { nb[0] = 0; return; }
    if (b == PPB2) { nb[PPB2] = NN; return; }
    long cum0 = 0;
#pragma unroll
    for (int r = 0; r < 4; r++) cum0 += rowptr2[(size_t)r * (NN + 1)];
    long target = (long)b * EE / PPB2 + cum0;
    int lo = 0, hi = NN;
    while (lo < hi) {
        int mid = (lo + hi) >> 1;
        long cm = 0;
#pragma unroll
        for (int r = 0; r < 4; r++) cm += rowptr2[(size_t)r * (NN + 1) + mid];
        if (cm < target) lo = mid + 1; else hi = mid;
    }
    nb[b] = lo;
}

// ---------------- input MLP: writes T-linear + z-linear ---------------------

__global__ void k_mlp0(const float* __restrict__ x, const float* __restrict__ W0,
                       const float* __restrict__ b0, __half* __restrict__ outT,
                       __half* __restrict__ outZ, const float* __restrict__ dinv) {
    int t = blockIdx.x * 256 + threadIdx.x;
    int n = t >> 5, o = t & 31;
    if (n < NN) {
        float acc = b0[o];
#pragma unroll
        for (int i = 0; i < 3; i++) acc += x[n * 3 + i] * W0[i * 32 + o];
        float h = fmaxf(acc, 0.f);
        outT[t] = __float2half(h);
        outZ[t] = __float2half(dinv[n] * h);
    }
}

// ---------------- phased z-space propagation v5 -----------------------------

__device__ inline void accum_range4(const int* __restrict__ rp,
                                    const int* __restrict__ csr,
                                    const __half* __restrict__ zc,
                                    int n, float4& lo, float4& hi) {
    int j = rp[n], end = rp[n + 1];
    for (; j + 4 <= end; j += 4) {
        int4 e = *reinterpret_cast<const int4*>(csr + j);
        uint4 u0 = *reinterpret_cast<const uint4*>(zc + (size_t)e.x * 32);
        uint4 u1 = *reinterpret_cast<const uint4*>(zc + (size_t)e.y * 32);
        uint4 u2 = *reinterpret_cast<const uint4*>(zc + (size_t)e.z * 32);
        uint4 u3 = *reinterpret_cast<const uint4*>(zc + (size_t)e.w * 32);
        add8(lo, hi, u0); add8(lo, hi, u1); add8(lo, hi, u2); add8(lo, hi, u3);
    }
    for (; j < end; j++) {
        uint4 u = *reinterpret_cast<const uint4*>(zc + (size_t)csr[j] * 32);
        add8(lo, hi, u);
    }
}

__global__ __launch_bounds__(256, 8) void k_prop2(const int* __restrict__ rowptr2,
                                                  const int* __restrict__ csr,
                                                  const int* __restrict__ nb,
                                                  const __half* __restrict__ zin,
                                                  __half* __restrict__ zout,
                                                  const float* __restrict__ d2) {
    int tid = threadIdx.x;
    int g = tid >> 2, c = tid & 3;          // 64 node-groups, 4 lanes each
    int start = nb[blockIdx.x], end = nb[blockIdx.x + 1];
    const __half* zc = zin + c * 8;
    int n0 = start + g;
    float4 zz = make_float4(0.f, 0.f, 0.f, 0.f);
    float4 l0 = zz, h0 = zz, l1 = zz, h1 = zz, l2 = zz, h2 = zz;
    for (int r = 0; r < 4; r++) {
        const int* rp = rowptr2 + (size_t)r * (NN + 1);
        if (n0       < end) accum_range4(rp, csr, zc, n0,       l0, h0);
        if (n0 + 64  < end) accum_range4(rp, csr, zc, n0 + 64,  l1, h1);
        if (n0 + 128 < end) accum_range4(rp, csr, zc, n0 + 128, l2, h2);
        // no barrier: edge-balance keeps blocks phase-aligned
    }
    if (n0 < end)
        st_h8s(zout + (size_t)n0 * 32 + c * 8, l0, h0, d2[n0]);
    if (n0 + 64 < end)
        st_h8s(zout + (size_t)(n0 + 64) * 32 + c * 8, l1, h1, d2[n0 + 64]);
    if (n0 + 128 < end)
        st_h8s(zout + (size_t)(n0 + 128) * 32 + c * 8, l2, h2, d2[n0 + 128]);
}

// ---------------- fused Cheb combine v7 -------------------------------------
// v5 structure (1 output/thread, 8-node batches, 96 W floats — proven VGPR 84,
// no spill) with ONE change: LDS staging keeps raw fp16 (lossless copy;
// convert at consume). Per-thread ds_read_b128 per batch: 24 -> 12.
// Double-buffered, prefetch, one barrier per batch.

__global__ __launch_bounds__(256) void k_cheb(const __half* __restrict__ T0,
                                              const __half* __restrict__ Z1,
                                              const __half* __restrict__ Z2,
                                              const __half* __restrict__ res,
                                              __half* __restrict__ outT,
                                              __half* __restrict__ outZ,
                                              const float* __restrict__ W,
                                              const float* __restrict__ b,
                                              const float* __restrict__ sarr,
                                              const float* __restrict__ dinv,
                                              int do_relu, int has_res, int write_z) {
    __shared__ __align__(16) __half A[2][3][256];   // raw fp16 rows, 3KB
    __shared__ __align__(16) float R[2][8][32];     // res fp32, 2KB
    int t = threadIdx.x;
    int o = t & 31, ng = t >> 5;
    int a = t >> 6, j = t & 63;

    float w0p[32], w1c[32], w2p[32];
#pragma unroll
    for (int i = 0; i < 32; i++) {
        float wa = W[i * 32 + o];
        float wb = W[1024 + i * 32 + o];
        float wc = W[2048 + i * 32 + o];
        w0p[i] = wa - wc;
        w1c[i] = wb;
        w2p[i] = 2.f * wc;
    }
    float bias = b[o];

    bool active = (a < 3) || has_res;
    const __half* srcp = (a == 0) ? T0 : (a == 1) ? Z1 : (a == 2) ? Z2 : res;
    int bt0 = blockIdx.x * CBATCH2;

    // prologue: stage batch 0 into buffer 0 (uint2 = 4 halfs per thread)
    if (active) {
        uint2 u = *(reinterpret_cast<const uint2*>(srcp + (size_t)bt0 * 256) + j);
        if (a < 3) {
            *reinterpret_cast<uint2*>(&A[0][a][j * 4]) = u;
        } else {
            __half2 h0 = *reinterpret_cast<__half2*>(&u.x);
            __half2 h1 = *reinterpret_cast<__half2*>(&u.y);
            float2 f0 = __half22float2(h0), f1 = __half22float2(h1);
            float* dst = &R[0][j >> 3][(j & 7) * 4];
            dst[0] = f0.x; dst[1] = f0.y; dst[2] = f1.x; dst[3] = f1.y;
        }
    }
    __syncthreads();

    int cur = 0;
    for (int bt = bt0; bt < bt0 + CBATCH2; bt++) {
        uint2 un;
        bool pf = active && (bt + 1 < bt0 + CBATCH2);
        if (pf)
            un = *(reinterpret_cast<const uint2*>(srcp + (size_t)(bt + 1) * 256) + j);

        size_t base = (size_t)bt * 256;
        float accA = bias + (has_res ? R[cur][ng][o] : 0.f);
        float accB = 0.f;
        const __half* rowT = &A[cur][0][ng * 32];
        const __half* row1 = &A[cur][1][ng * 32];
        const __half* row2 = &A[cur][2][ng * 32];
#pragma unroll
        for (int q = 0; q < 4; q++) {
            uint4 uT = *reinterpret_cast<const uint4*>(rowT + q * 8);
            uint4 u1 = *reinterpret_cast<const uint4*>(row1 + q * 8);
            uint4 u2 = *reinterpret_cast<const uint4*>(row2 + q * 8);
            float fT[8], f1[8], f2[8];
            cvt8(uT, fT); cvt8(u1, f1); cvt8(u2, f2);
#pragma unroll
            for (int k = 0; k < 8; k++) {
                int i = q * 8 + k;
                accA += fT[k] * w0p[i];
                accB += f1[k] * w1c[i] + f2[k] * w2p[i];
            }
        }
        int node = bt * 8 + ng;
        float v = accA + sarr[node] * accB;
        if (do_relu) v = fmaxf(v, 0.f);
        outT[base + ng * 32 + o] = __float2half(v);
        if (write_z)
            outZ[base + ng * 32 + o] = __float2half(dinv[node] * v);

        if (pf) {
            if (a < 3) {
                *reinterpret_cast<uint2*>(&A[cur ^ 1][a][j * 4]) = un;
            } else {
                __half2 h0 = *reinterpret_cast<__half2*>(&un.x);
                __half2 h1 = *reinterpret_cast<__half2*>(&un.y);
                float2 f0 = __half22float2(h0), f1 = __half22float2(h1);
                float* dst = &R[cur ^ 1][j >> 3][(j & 7) * 4];
                dst[0] = f0.x; dst[1] = f0.y; dst[2] = f1.x; dst[3] = f1.y;
            }
        }
        __syncthreads();   // cur fully read + cur^1 staged
        cur ^= 1;
    }
}

// ---------------- final head ------------------------------------------------

__global__ void k_final(const __half* __restrict__ X, const float* __restrict__ W1,
                        const float* __restrict__ b1, float* __restrict__ out) {
    int n = blockIdx.x * 256 + threadIdx.x;
    if (n < NN) {
        float acc = b1[0];
        const __half* xp = X + (size_t)n * 32;
#pragma unroll
        for (int c = 0; c < 8; c++) {
            float4 v = ld_h4(xp + c * 4);
            acc += v.x * W1[c * 4 + 0] + v.y * W1[c * 4 + 1] +
                   v.z * W1[c * 4 + 2] + v.w * W1[c * 4 + 3];
        }
        out[n] = acc;
    }
}

extern "C" void kernel_launch(void* const* d_in, const int* in_sizes, int n_in,
                              void* d_out, int out_size, void* d_ws, size_t ws_size,
                              hipStream_t stream) {
    const float* x    = (const float*)d_in[0];
    const int*   ei   = (const int*)d_in[1];
    const float* W0   = (const float*)d_in[2];
    const float* b0   = (const float*)d_in[3];
    const float* c11W = (const float*)d_in[4];
    const float* c11b = (const float*)d_in[5];
    const float* c12W = (const float*)d_in[6];
    const float* c12b = (const float*)d_in[7];
    const float* c21W = (const float*)d_in[8];
    const float* c21b = (const float*)d_in[9];
    const float* c22W = (const float*)d_in[10];
    const float* c22b = (const float*)d_in[11];
    const float* W1   = (const float*)d_in[12];
    const float* b1   = (const float*)d_in[13];
    float* out = (float*)d_out;

    char* ws = (char*)d_ws;
    float* dinv = (float*)ws;  ws = ALIGN64(ws + (size_t)NN * 4);
    float* d2 = (float*)ws;    ws = ALIGN64(ws + (size_t)NN * 4);
    float* sarr = (float*)ws;  ws = ALIGN64(ws + (size_t)NN * 4);
    int* rowptr2 = (int*)ws;   ws = ALIGN64(ws + (size_t)4 * (NN + 1) * 4);
    int* nb = (int*)ws;        ws = ALIGN64(ws + (size_t)(PPB2 + 1) * 4);
    unsigned* partial = (unsigned*)ws;
    ws = ALIGN64(ws + (size_t)HG3 * HS3 * (HB3 / 4) * 4);          // 17.0 MB
    int* fs = (int*)ws;        ws = ALIGN64(ws + (size_t)(NKEY + 1) * NA * 4);
    int* btot = (int*)ws;      ws = ALIGN64(ws + (size_t)NKEY * 4);
    int* bstart2 = (int*)ws;   ws = ALIGN64(ws + (size_t)(NKEY + 1) * 4);
    int* ebkt = (int*)ws;      ws = ALIGN64(ws + (size_t)EE * 4);  // 12.8 MB
    int* csr = (int*)ws;       ws = ALIGN64(ws + (size_t)EE * 4);  // 12.8 MB
    __half* F0 = (__half*)ws;  ws = ALIGN64(ws + (size_t)NN * HID * 2);
    __half* F1 = (__half*)ws;  ws = ALIGN64(ws + (size_t)NN * HID * 2);
    __half* Zin = (__half*)ws; ws = ALIGN64(ws + (size_t)NN * HID * 2);
    __half* Zb1 = (__half*)ws; ws = ALIGN64(ws + (size_t)NN * HID * 2);
    __half* Zb2 = (__half*)ws; ws = ALIGN64(ws + (size_t)NN * HID * 2);

    // src degrees -> dinv, d2, s
    k_hist<<<HG3 * HS3, 256, 0, stream>>>(ei, partial);
    k_hredscale<<<NN / 4 / 256 + 1, 256, 0, stream>>>(partial, dinv, d2, sarr);

    // two-stage sort -> range-segmented exact CSR + rowptr2
    k_stageA<<<NA, 256, 0, stream>>>(ei, fs, ebkt);
    k_btot<<<NKEY, 256, 0, stream>>>(fs, btot);
    k_bscan<<<1, 256, 0, stream>>>(btot, bstart2);
    k_stageB<<<NBKT, 1024, 0, stream>>>(fs, bstart2, ebkt, rowptr2, csr);

    // edge-balanced block partition for phased prop
    k_bal<<<(PPB2 + 256) / 256, 256, 0, stream>>>(rowptr2, nb);

    k_mlp0<<<NN * HID / 256, 256, 0, stream>>>(x, W0, b0, F0, Zin, dinv);

    auto conv = [&](const __half* T0, const __half* res, __half* outT,
                    const float* W, const float* b, int relu, int has_res, int wz) {
        k_prop2<<<PPB2, 256, 0, stream>>>(rowptr2, csr, nb, Zin, Zb1, d2);
        k_prop2<<<PPB2, 256, 0, stream>>>(rowptr2, csr, nb, Zb1, Zb2, d2);
        k_cheb<<<CBLK2, 256, 0, stream>>>(T0, Zb1, Zb2, res, outT, Zin,
                                          W, b, sarr, dinv, relu, has_res, wz);
    };

    conv(F0, nullptr, F1, c11W, c11b, 1, 0, 1);   // block1 conv1
    conv(F1, F0,      F0, c12W, c12b, 1, 1, 1);   // block1 conv2 (+res)
    conv(F0, nullptr, F1, c21W, c21b, 1, 0, 1);   // block2 conv1
    conv(F1, F0,      F0, c22W, c22b, 1, 1, 0);   // block2 conv2 (+res, no z)

    k_final<<<(NN + 255) / 256, 256, 0, stream>>>(F0, W1, b1, out);
}

// Round 17
// 729.939 us; speedup vs baseline: 2.0511x; 1.0938x over previous
//
#include <hip/hip_runtime.h>
#include <hip/hip_fp16.h>

#define NN 200000
#define EE 3200000
#define HID 32

// src-degree histogram v3: byte counters, 16KB tiles, packed partials
#define HB3 16384            // bins per group (16 KB LDS as bytes)
#define HG3 13               // 13*16384 = 212992 >= NN
#define HS3 80               // slices: grid = 13*80 = 1040
#define ESL3 (EE / HS3)      // 40000 edges per slice

// block-major two-stage dst sort, keyed by (dst>>10, src_range)
#define CH 8000    // edges per stage-A block (32 KB private region)
#define NA 400     // EE / CH
#define NBKT 196   // dst buckets of 1024
#define NKEY (NBKT * 4)      // 784

// src ranges: 4 x 50000 nodes -> 3.2 MB z-slice fits a 4 MB XCD L2
#define RSZ 50000

// phased prop v5: edge-balanced, 2048 co-resident blocks, 4 lanes x 16B/node
#define PPB2 2048

// cheb combine v5 (champion): fp32-staged LDS, prefetch + dbuf + deep grid
#define CBLK2 3125
#define CBATCH2 8  // 3125*8*8 = 200000 = NN

#define ALIGN64(p) ((char*)(((uintptr_t)(p) + 63) & ~(uintptr_t)63))

__device__ inline int srcrg(int s) {
    return (s >= RSZ) + (s >= 2 * RSZ) + (s >= 3 * RSZ);
}

// ---------------- fp16 helpers ----------------------------------------------

__device__ inline float4 ld_h4(const __half* p) {
    uint2 u = *reinterpret_cast<const uint2*>(p);
    __half2 a = *reinterpret_cast<__half2*>(&u.x);
    __half2 b = *reinterpret_cast<__half2*>(&u.y);
    float2 fa = __half22float2(a), fb = __half22float2(b);
    return make_float4(fa.x, fa.y, fb.x, fb.y);
}

__device__ inline void st_h4(__half* p, float4 v) {
    __half2 a = __floats2half2_rn(v.x, v.y);
    __half2 b = __floats2half2_rn(v.z, v.w);
    uint2 u;
    u.x = *reinterpret_cast<unsigned*>(&a);
    u.y = *reinterpret_cast<unsigned*>(&b);
    *reinterpret_cast<uint2*>(p) = u;
}

// accumulate 8 halfs (one uint4) into two float4s
__device__ inline void add8(float4& lo, float4& hi, uint4 u) {
    __half2 h0 = *reinterpret_cast<__half2*>(&u.x);
    __half2 h1 = *reinterpret_cast<__half2*>(&u.y);
    __half2 h2 = *reinterpret_cast<__half2*>(&u.z);
    __half2 h3 = *reinterpret_cast<__half2*>(&u.w);
    float2 f0 = __half22float2(h0), f1 = __half22float2(h1);
    float2 f2 = __half22float2(h2), f3 = __half22float2(h3);
    lo.x += f0.x; lo.y += f0.y; lo.z += f1.x; lo.w += f1.y;
    hi.x += f2.x; hi.y += f2.y; hi.z += f3.x; hi.w += f3.y;
}

// scale two float4s and store as 8 halfs (16B)
__device__ inline void st_h8s(__half* p, float4 lo, float4 hi, float sc) {
    __half2 h0 = __floats2half2_rn(sc * lo.x, sc * lo.y);
    __half2 h1 = __floats2half2_rn(sc * lo.z, sc * lo.w);
    __half2 h2 = __floats2half2_rn(sc * hi.x, sc * hi.y);
    __half2 h3 = __floats2half2_rn(sc * hi.z, sc * hi.w);
    uint4 u;
    u.x = *reinterpret_cast<unsigned*>(&h0);
    u.y = *reinterpret_cast<unsigned*>(&h1);
    u.z = *reinterpret_cast<unsigned*>(&h2);
    u.w = *reinterpret_cast<unsigned*>(&h3);
    *reinterpret_cast<uint4*>(p) = u;
}

// ---------------- src-degree histogram (byte-packed) ------------------------

__global__ __launch_bounds__(256) void k_hist(const int* __restrict__ vals,
                                              unsigned* __restrict__ partial) {
    __shared__ unsigned h[HB3 / 4];
    int blk = blockIdx.x;
    int g = blk % HG3, s = blk / HG3;
    int base = g * HB3;
    for (int i = threadIdx.x; i < HB3 / 4; i += 256) h[i] = 0;
    __syncthreads();
    const int4* p4 = reinterpret_cast<const int4*>(vals + (size_t)s * ESL3);
    for (int i = threadIdx.x; i < ESL3 / 4; i += 256) {
        int4 v = p4[i];
        int a0 = v.x - base, a1 = v.y - base, a2 = v.z - base, a3 = v.w - base;
        if ((unsigned)a0 < HB3) atomicAdd(&h[a0 >> 2], 1u << ((a0 & 3) * 8));
        if ((unsigned)a1 < HB3) atomicAdd(&h[a1 >> 2], 1u << ((a1 & 3) * 8));
        if ((unsigned)a2 < HB3) atomicAdd(&h[a2 >> 2], 1u << ((a2 & 3) * 8));
        if ((unsigned)a3 < HB3) atomicAdd(&h[a3 >> 2], 1u << ((a3 & 3) * 8));
    }
    __syncthreads();
    unsigned* out = partial + ((size_t)g * HS3 + s) * (HB3 / 4);
    for (int i = threadIdx.x; i < HB3 / 4; i += 256) out[i] = h[i];
}

__global__ void k_hredscale(const unsigned* __restrict__ partial,
                            float* __restrict__ dinv, float* __restrict__ d2,
                            float* __restrict__ sarr) {
    int q = blockIdx.x * 256 + threadIdx.x;
    if (q >= NN / 4) return;
    int nb = q * 4;
    int g = nb >> 14;
    int col = (nb & (HB3 - 1)) >> 2;
    const unsigned* p = partial + (size_t)g * HS3 * (HB3 / 4) + col;
    unsigned ssum = 0;
#pragma unroll
    for (int s = 0; s < HS3; s++) ssum += p[(size_t)s * (HB3 / 4)];
#pragma unroll
    for (int k = 0; k < 4; k++) {
        int n = nb + k;
        int d = (ssum >> (k * 8)) & 255;
        float di = d > 0 ? rsqrtf((float)d) : 0.f;
        dinv[n] = di;
        d2[n] = -di * di;
        sarr[n] = d > 0 ? 1.f / di : 0.f;
    }
}

// ---------------- stage A: block-major coarse sort by (bucket, src-range) ---

__global__ __launch_bounds__(256) void k_stageA(const int* __restrict__ ei,
                                                int* __restrict__ fs,
                                                int* __restrict__ ebkt) {
    __shared__ int sdst[CH];
    __shared__ int hist[NKEY], excl[NKEY + 1], rank[NKEY], s1[256];
    int blk = blockIdx.x, tid = threadIdx.x;
    for (int i = tid; i < NKEY; i += 256) { hist[i] = 0; rank[i] = 0; }
    __syncthreads();
    const int* dptr = ei + EE + (size_t)blk * CH;
    const int* sptr = ei + (size_t)blk * CH;
    for (int i = tid; i < CH; i += 256) {
        int d = dptr[i], s = sptr[i];
        sdst[i] = d;
        atomicAdd(&hist[(d >> 10) * 4 + srcrg(s)], 1);
    }
    __syncthreads();
    int b4 = tid * 4;
    int v0 = (b4 < NKEY) ? hist[b4] : 0;
    int v1 = (b4 + 1 < NKEY) ? hist[b4 + 1] : 0;
    int v2 = (b4 + 2 < NKEY) ? hist[b4 + 2] : 0;
    int v3 = (b4 + 3 < NKEY) ? hist[b4 + 3] : 0;
    int ts = v0 + v1 + v2 + v3;
    s1[tid] = ts;
    __syncthreads();
    for (int off = 1; off < 256; off <<= 1) {
        int t2 = (tid >= off) ? s1[tid - off] : 0;
        __syncthreads();
        s1[tid] += t2;
        __syncthreads();
    }
    int te = s1[tid] - ts;
    if (b4 < NKEY) excl[b4] = te;
    if (b4 + 1 < NKEY) excl[b4 + 1] = te + v0;
    if (b4 + 2 < NKEY) excl[b4 + 2] = te + v0 + v1;
    if (b4 + 3 < NKEY) excl[b4 + 3] = te + v0 + v1 + v2;
    if (tid == 0) excl[NKEY] = CH;
    __syncthreads();
    for (int k = tid; k <= NKEY; k += 256) fs[(size_t)k * NA + blk] = excl[k];
    int base = blk * CH;
    for (int i = tid; i < CH; i += 256) {
        int d = sdst[i], s = sptr[i];
        int key = (d >> 10) * 4 + srcrg(s);
        int r = atomicAdd(&rank[key], 1);
        ebkt[base + excl[key] + r] = (s << 10) | (d & 1023);
    }
}

// ---------------- key totals + exclusive scan (range-major output) ----------

__global__ void k_btot(const int* __restrict__ fs, int* __restrict__ btot) {
    __shared__ int s[256];
    int k = blockIdx.x, tid = threadIdx.x;
    int sum = 0;
    for (int blk = tid; blk < NA; blk += 256)
        sum += fs[(size_t)(k + 1) * NA + blk] - fs[(size_t)k * NA + blk];
    s[tid] = sum;
    __syncthreads();
    for (int off = 128; off > 0; off >>= 1) {
        if (tid < off) s[tid] += s[tid + off];
        __syncthreads();
    }
    if (tid == 0) btot[k] = s[0];
}

__global__ void k_bscan(const int* __restrict__ btot, int* __restrict__ bstart2) {
    __shared__ int s[256];
    __shared__ int carry;
    int tid = threadIdx.x;
    if (tid == 0) carry = 0;
    __syncthreads();
    for (int base = 0; base < NKEY; base += 256) {
        int m = base + tid;
        int v = 0;
        if (m < NKEY) v = btot[(m % NBKT) * 4 + (m / NBKT)];
        s[tid] = v;
        __syncthreads();
        for (int off = 1; off < 256; off <<= 1) {
            int t = (tid >= off) ? s[tid - off] : 0;
            __syncthreads();
            s[tid] += t;
            __syncthreads();
        }
        int excl = s[tid] - v + carry;
        if (m < NKEY) bstart2[m] = excl;
        __syncthreads();
        if (tid == 0) carry += s[255];
        __syncthreads();
    }
    if (tid == 0) bstart2[NKEY] = EE;
}

// ---------------- stage B: bucket -> range-segmented exact CSR + rowptr2 ----

__global__ __launch_bounds__(1024) void k_stageB(const int* __restrict__ fs,
                                                 const int* __restrict__ bstart2,
                                                 const int* __restrict__ ebkt,
                                                 int* __restrict__ rowptr2,
                                                 int* __restrict__ csr) {
    __shared__ int ls0[NA], llen[NA];
    __shared__ int deg[4096], excl[4096], rank[4096], s1[1024];
    __shared__ int sb[4], seg0[4];
    int b = blockIdx.x, tid = threadIdx.x;
    if (tid < NA) {
        int o0 = fs[(size_t)(4 * b) * NA + tid];
        int o1 = fs[(size_t)(4 * b + 4) * NA + tid];
        ls0[tid] = tid * CH + o0;
        llen[tid] = o1 - o0;
    }
    deg[tid] = 0; deg[tid + 1024] = 0; deg[tid + 2048] = 0; deg[tid + 3072] = 0;
    rank[tid] = 0; rank[tid + 1024] = 0; rank[tid + 2048] = 0; rank[tid + 3072] = 0;
    if (tid < 4) sb[tid] = bstart2[tid * NBKT + b];
    __syncthreads();
    int wave = tid >> 6, lane = tid & 63;   // 16 waves
    for (int f = wave; f < NA; f += 16) {
        int base = ls0[f], len = llen[f];
        for (int k = lane; k < len; k += 64) {
            int e = ebkt[base + k];
            int s = e >> 10, l = e & 1023;
            atomicAdd(&deg[srcrg(s) * 1024 + l], 1);
        }
    }
    __syncthreads();
    int v0 = deg[4 * tid], v1 = deg[4 * tid + 1];
    int v2 = deg[4 * tid + 2], v3 = deg[4 * tid + 3];
    int ts = v0 + v1 + v2 + v3;
    s1[tid] = ts;
    __syncthreads();
    for (int off = 1; off < 1024; off <<= 1) {
        int t = (tid >= off) ? s1[tid - off] : 0;
        __syncthreads();
        s1[tid] += t;
        __syncthreads();
    }
    int te = s1[tid] - ts;
    excl[4 * tid] = te;
    excl[4 * tid + 1] = te + v0;
    excl[4 * tid + 2] = te + v0 + v1;
    excl[4 * tid + 3] = te + v0 + v1 + v2;
    __syncthreads();
    if (tid < 4) seg0[tid] = excl[tid * 1024];
    __syncthreads();
#pragma unroll
    for (int k = 0; k < 4; k++) {
        int m = 4 * tid + k;
        int rg = m >> 10, l = m & 1023;
        int node = (b << 10) + l;
        if (node <= NN)
            rowptr2[(size_t)rg * (NN + 1) + node] = sb[rg] + excl[m] - seg0[rg];
    }
    for (int f = wave; f < NA; f += 16) {
        int base = ls0[f], len = llen[f];
        for (int k = lane; k < len; k += 64) {
            int e = ebkt[base + k];
            int s = e >> 10, l = e & 1023;
            int rg = srcrg(s);
            int key = rg * 1024 + l;
            int r = atomicAdd(&rank[key], 1);
            csr[sb[rg] + (excl[key] - seg0[rg]) + r] = s;
        }
    }
}

// ---------------- edge-balanced block partition -----------------------------

__global__ void k_bal(const int* __restrict__ rowptr2, int* __restrict__ nb) {
    int b = blockIdx.x * 256 + threadIdx.x;
    if (b > PPB2) return;
    if (b == 0) { nb[0] = 0; return; }
    if (b == PPB2) { nb[PPB2] = NN; return; }
    long cum0 = 0;
#pragma unroll
    for (int r = 0; r < 4; r++) cum0 += rowptr2[(size_t)r * (NN + 1)];
    long target = (long)b * EE / PPB2 + cum0;
    int lo = 0, hi = NN;
    while (lo < hi) {
        int mid = (lo + hi) >> 1;
        long cm = 0;
#pragma unroll
        for (int r = 0; r < 4; r++) cm += rowptr2[(size_t)r * (NN + 1) + mid];
        if (cm < target) lo = mid + 1; else hi = mid;
    }
    nb[b] = lo;
}

// ---------------- input MLP: writes T-linear + z-linear ---------------------

__global__ void k_mlp0(const float* __restrict__ x, const float* __restrict__ W0,
                       const float* __restrict__ b0, __half* __restrict__ outT,
                       __half* __restrict__ outZ, const float* __restrict__ dinv) {
    int t = blockIdx.x * 256 + threadIdx.x;
    int n = t >> 5, o = t & 31;
    if (n < NN) {
        float acc = b0[o];
#pragma unroll
        for (int i = 0; i < 3; i++) acc += x[n * 3 + i] * W0[i * 32 + o];
        float h = fmaxf(acc, 0.f);
        outT[t] = __float2half(h);
        outZ[t] = __float2half(dinv[n] * h);
    }
}

// ---------------- phased z-space propagation v5 -----------------------------
// 2048 edge-balanced co-resident blocks x 256 thr; 4 lanes x 16B per node row
// (one 64B line per edge). Range-outer loop, no barrier (drift-aligned).

__device__ inline void accum_range4(const int* __restrict__ rp,
                                    const int* __restrict__ csr,
                                    const __half* __restrict__ zc,
                                    int n, float4& lo, float4& hi) {
    int j = rp[n], end = rp[n + 1];
    for (; j + 4 <= end; j += 4) {
        int4 e = *reinterpret_cast<const int4*>(csr + j);
        uint4 u0 = *reinterpret_cast<const uint4*>(zc + (size_t)e.x * 32);
        uint4 u1 = *reinterpret_cast<const uint4*>(zc + (size_t)e.y * 32);
        uint4 u2 = *reinterpret_cast<const uint4*>(zc + (size_t)e.z * 32);
        uint4 u3 = *reinterpret_cast<const uint4*>(zc + (size_t)e.w * 32);
        add8(lo, hi, u0); add8(lo, hi, u1); add8(lo, hi, u2); add8(lo, hi, u3);
    }
    for (; j < end; j++) {
        uint4 u = *reinterpret_cast<const uint4*>(zc + (size_t)csr[j] * 32);
        add8(lo, hi, u);
    }
}

__global__ __launch_bounds__(256, 8) void k_prop2(const int* __restrict__ rowptr2,
                                                  const int* __restrict__ csr,
                                                  const int* __restrict__ nb,
                                                  const __half* __restrict__ zin,
                                                  __half* __restrict__ zout,
                                                  const float* __restrict__ d2) {
    int tid = threadIdx.x;
    int g = tid >> 2, c = tid & 3;          // 64 node-groups, 4 lanes each
    int start = nb[blockIdx.x], end = nb[blockIdx.x + 1];
    const __half* zc = zin + c * 8;
    int n0 = start + g;
    float4 zz = make_float4(0.f, 0.f, 0.f, 0.f);
    float4 l0 = zz, h0 = zz, l1 = zz, h1 = zz, l2 = zz, h2 = zz;
    for (int r = 0; r < 4; r++) {
        const int* rp = rowptr2 + (size_t)r * (NN + 1);
        if (n0       < end) accum_range4(rp, csr, zc, n0,       l0, h0);
        if (n0 + 64  < end) accum_range4(rp, csr, zc, n0 + 64,  l1, h1);
        if (n0 + 128 < end) accum_range4(rp, csr, zc, n0 + 128, l2, h2);
        // no barrier: edge-balance keeps blocks phase-aligned
    }
    if (n0 < end)
        st_h8s(zout + (size_t)n0 * 32 + c * 8, l0, h0, d2[n0]);
    if (n0 + 64 < end)
        st_h8s(zout + (size_t)(n0 + 64) * 32 + c * 8, l1, h1, d2[n0 + 64]);
    if (n0 + 128 < end)
        st_h8s(zout + (size_t)(n0 + 128) * 32 + c * 8, l2, h2, d2[n0 + 128]);
}

// ---------------- fused Cheb combine v5 (champion config) -------------------
// fp32-staged LDS (proven: VGPR 84, no spill, 56.5 us), register prefetch of
// batch t+1, double-buffered LDS, one barrier per batch, grid 3125 x 8.

__global__ __launch_bounds__(256) void k_cheb(const __half* __restrict__ T0,
                                              const __half* __restrict__ Z1,
                                              const __half* __restrict__ Z2,
                                              const __half* __restrict__ res,
                                              __half* __restrict__ outT,
                                              __half* __restrict__ outZ,
                                              const float* __restrict__ W,
                                              const float* __restrict__ b,
                                              const float* __restrict__ sarr,
                                              const float* __restrict__ dinv,
                                              int do_relu, int has_res, int write_z) {
    __shared__ __align__(16) float A[2][8][100];
    __shared__ float R[2][8][32];
    int t = threadIdx.x;
    int o = t & 31, ng = t >> 5;
    int a = t >> 6, j = t & 63;

    float w0p[32], w1c[32], w2p[32];
#pragma unroll
    for (int i = 0; i < 32; i++) {
        float wa = W[i * 32 + o];
        float wb = W[1024 + i * 32 + o];
        float wc = W[2048 + i * 32 + o];
        w0p[i] = wa - wc;
        w1c[i] = wb;
        w2p[i] = 2.f * wc;
    }
    float bias = b[o];

    int nn = j >> 3, ii = (j & 7) * 4;
    bool active = (a < 3) || has_res;
    const __half* srcp = (a == 0) ? T0 : (a == 1) ? Z1 : (a == 2) ? Z2 : res;
    int bt0 = blockIdx.x * CBATCH2;

    // prologue: stage batch 0 into buffer 0
    if (active) {
        uint2 u = *(reinterpret_cast<const uint2*>(srcp + (size_t)bt0 * 256) + j);
        __half2 h0 = *reinterpret_cast<__half2*>(&u.x);
        __half2 h1 = *reinterpret_cast<__half2*>(&u.y);
        float2 f0 = __half22float2(h0), f1 = __half22float2(h1);
        float* dst = (a < 3) ? &A[0][nn][a * 32 + ii] : &R[0][nn][ii];
        dst[0] = f0.x; dst[1] = f0.y; dst[2] = f1.x; dst[3] = f1.y;
    }
    __syncthreads();

    int cur = 0;
    for (int bt = bt0; bt < bt0 + CBATCH2; bt++) {
        uint2 un;
        bool pf = active && (bt + 1 < bt0 + CBATCH2);
        if (pf)
            un = *(reinterpret_cast<const uint2*>(srcp + (size_t)(bt + 1) * 256) + j);

        size_t base = (size_t)bt * 256;
        float accA = bias + (has_res ? R[cur][ng][o] : 0.f);
        float accB = 0.f;
#pragma unroll
        for (int q = 0; q < 8; q++) {
            float4 t0 = *reinterpret_cast<float4*>(&A[cur][ng][q * 4]);
            float4 z1 = *reinterpret_cast<float4*>(&A[cur][ng][32 + q * 4]);
            float4 z2 = *reinterpret_cast<float4*>(&A[cur][ng][64 + q * 4]);
            accA += t0.x * w0p[4*q] + t0.y * w0p[4*q+1] + t0.z * w0p[4*q+2] + t0.w * w0p[4*q+3];
            accB += z1.x * w1c[4*q] + z1.y * w1c[4*q+1] + z1.z * w1c[4*q+2] + z1.w * w1c[4*q+3];
            accB += z2.x * w2p[4*q] + z2.y * w2p[4*q+1] + z2.z * w2p[4*q+2] + z2.w * w2p[4*q+3];
        }
        int node = bt * 8 + ng;
        float v = accA + sarr[node] * accB;
        if (do_relu) v = fmaxf(v, 0.f);
        outT[base + ng * 32 + o] = __float2half(v);
        if (write_z)
            outZ[base + ng * 32 + o] = __float2half(dinv[node] * v);

        if (pf) {
            __half2 h0 = *reinterpret_cast<__half2*>(&un.x);
            __half2 h1 = *reinterpret_cast<__half2*>(&un.y);
            float2 f0 = __half22float2(h0), f1 = __half22float2(h1);
            float* dst = (a < 3) ? &A[cur ^ 1][nn][a * 32 + ii]
                                 : &R[cur ^ 1][nn][ii];
            dst[0] = f0.x; dst[1] = f0.y; dst[2] = f1.x; dst[3] = f1.y;
        }
        __syncthreads();
        cur ^= 1;
    }
}

// ---------------- final head ------------------------------------------------

__global__ void k_final(const __half* __restrict__ X, const float* __restrict__ W1,
                        const float* __restrict__ b1, float* __restrict__ out) {
    int n = blockIdx.x * 256 + threadIdx.x;
    if (n < NN) {
        float acc = b1[0];
        const __half* xp = X + (size_t)n * 32;
#pragma unroll
        for (int c = 0; c < 8; c++) {
            float4 v = ld_h4(xp + c * 4);
            acc += v.x * W1[c * 4 + 0] + v.y * W1[c * 4 + 1] +
                   v.z * W1[c * 4 + 2] + v.w * W1[c * 4 + 3];
        }
        out[n] = acc;
    }
}

extern "C" void kernel_launch(void* const* d_in, const int* in_sizes, int n_in,
                              void* d_out, int out_size, void* d_ws, size_t ws_size,
                              hipStream_t stream) {
    const float* x    = (const float*)d_in[0];
    const int*   ei   = (const int*)d_in[1];
    const float* W0   = (const float*)d_in[2];
    const float* b0   = (const float*)d_in[3];
    const float* c11W = (const float*)d_in[4];
    const float* c11b = (const float*)d_in[5];
    const float* c12W = (const float*)d_in[6];
    const float* c12b = (const float*)d_in[7];
    const float* c21W = (const float*)d_in[8];
    const float* c21b = (const float*)d_in[9];
    const float* c22W = (const float*)d_in[10];
    const float* c22b = (const float*)d_in[11];
    const float* W1   = (const float*)d_in[12];
    const float* b1   = (const float*)d_in[13];
    float* out = (float*)d_out;

    char* ws = (char*)d_ws;
    float* dinv = (float*)ws;  ws = ALIGN64(ws + (size_t)NN * 4);
    float* d2 = (float*)ws;    ws = ALIGN64(ws + (size_t)NN * 4);
    float* sarr = (float*)ws;  ws = ALIGN64(ws + (size_t)NN * 4);
    int* rowptr2 = (int*)ws;   ws = ALIGN64(ws + (size_t)4 * (NN + 1) * 4);
    int* nb = (int*)ws;        ws = ALIGN64(ws + (size_t)(PPB2 + 1) * 4);
    unsigned* partial = (unsigned*)ws;
    ws = ALIGN64(ws + (size_t)HG3 * HS3 * (HB3 / 4) * 4);          // 17.0 MB
    int* fs = (int*)ws;        ws = ALIGN64(ws + (size_t)(NKEY + 1) * NA * 4);
    int* btot = (int*)ws;      ws = ALIGN64(ws + (size_t)NKEY * 4);
    int* bstart2 = (int*)ws;   ws = ALIGN64(ws + (size_t)(NKEY + 1) * 4);
    int* ebkt = (int*)ws;      ws = ALIGN64(ws + (size_t)EE * 4);  // 12.8 MB
    int* csr = (int*)ws;       ws = ALIGN64(ws + (size_t)EE * 4);  // 12.8 MB
    __half* F0 = (__half*)ws;  ws = ALIGN64(ws + (size_t)NN * HID * 2);
    __half* F1 = (__half*)ws;  ws = ALIGN64(ws + (size_t)NN * HID * 2);
    __half* Zin = (__half*)ws; ws = ALIGN64(ws + (size_t)NN * HID * 2);
    __half* Zb1 = (__half*)ws; ws = ALIGN64(ws + (size_t)NN * HID * 2);
    __half* Zb2 = (__half*)ws; ws = ALIGN64(ws + (size_t)NN * HID * 2);

    // src degrees -> dinv, d2, s
    k_hist<<<HG3 * HS3, 256, 0, stream>>>(ei, partial);
    k_hredscale<<<NN / 4 / 256 + 1, 256, 0, stream>>>(partial, dinv, d2, sarr);

    // two-stage sort -> range-segmented exact CSR + rowptr2
    k_stageA<<<NA, 256, 0, stream>>>(ei, fs, ebkt);
    k_btot<<<NKEY, 256, 0, stream>>>(fs, btot);
    k_bscan<<<1, 256, 0, stream>>>(btot, bstart2);
    k_stageB<<<NBKT, 1024, 0, stream>>>(fs, bstart2, ebkt, rowptr2, csr);

    // edge-balanced block partition for phased prop
    k_bal<<<(PPB2 + 256) / 256, 256, 0, stream>>>(rowptr2, nb);

    k_mlp0<<<NN * HID / 256, 256, 0, stream>>>(x, W0, b0, F0, Zin, dinv);

    auto conv = [&](const __half* T0, const __half* res, __half* outT,
                    const float* W, const float* b, int relu, int has_res, int wz) {
        k_prop2<<<PPB2, 256, 0, stream>>>(rowptr2, csr, nb, Zin, Zb1, d2);
        k_prop2<<<PPB2, 256, 0, stream>>>(rowptr2, csr, nb, Zb1, Zb2, d2);
        k_cheb<<<CBLK2, 256, 0, stream>>>(T0, Zb1, Zb2, res, outT, Zin,
                                          W, b, sarr, dinv, relu, has_res, wz);
    };

    conv(F0, nullptr, F1, c11W, c11b, 1, 0, 1);   // block1 conv1
    conv(F1, F0,      F0, c12W, c12b, 1, 1, 1);   // block1 conv2 (+res)
    conv(F0, nullptr, F1, c21W, c21b, 1, 0, 1);   // block2 conv1
    conv(F1, F0,      F0, c22W, c22b, 1, 1, 0);   // block2 conv2 (+res, no z)

    k_final<<<(NN + 255) / 256, 256, 0, stream>>>(F0, W1, b1, out);
}